// Round 10
// baseline (1673.166 us; speedup 1.0000x reference)
//
#include <hip/hip_runtime.h>

#define SEQ   1024
#define BATCH 512
#define HID   128
#define GC    512   // 4 gates * HID

typedef __attribute__((ext_vector_type(8))) short          short8v;
typedef __attribute__((ext_vector_type(4))) float          float4v;
typedef __attribute__((ext_vector_type(2))) float          float2v;
typedef __attribute__((ext_vector_type(4))) unsigned short ushort4v;
typedef __attribute__((ext_vector_type(8))) unsigned short ushort8v;

__device__ __forceinline__ unsigned short f2bf(float f) {
    union { float f; unsigned u; } v; v.f = f;
    return (unsigned short)((v.u + 0x7fffu + ((v.u >> 16) & 1u)) >> 16);
}
__device__ __forceinline__ float bf2f(unsigned short u) {
    union { unsigned u; float f; } v; v.u = ((unsigned)u) << 16;
    return v.f;
}
__device__ __forceinline__ float fast_cos(float x) {
    return __builtin_amdgcn_cosf(x * 0.15915494309189535f);   // v_cos takes revolutions
}
__device__ __forceinline__ float fast_sigmoid(float x) {
    return __builtin_amdgcn_rcpf(1.0f + __builtin_amdgcn_exp2f(-1.4426950408889634f * x));
}
__device__ __forceinline__ float fast_tanh(float x) {
    return 1.0f - 2.0f * __builtin_amdgcn_rcpf(1.0f + __builtin_amdgcn_exp2f(2.8853900817779268f * x));
}

// DPP helper: returns src shifted by CTRL, invalid/masked lanes get 1.0f
template<int CTRL, int RM>
__device__ __forceinline__ float dpp1(float v) {
    union { float f; int i; } s, o, r;
    s.f = v; o.f = 1.0f;
    r.i = __builtin_amdgcn_update_dpp(o.i, s.i, CTRL, RM, 0xf, false);
    return r.f;
}

// raw barrier: drains LDS only; global loads/stores stay in flight across it
#define BAR() do { asm volatile("s_waitcnt lgkmcnt(0)" ::: "memory");  \
                   __builtin_amdgcn_s_barrier();                       \
                   __builtin_amdgcn_sched_barrier(0); } while (0)

// ---------------------------------------------------------------------------
// Kernel 0: X f32 -> bf16 streaming convert (chunk slice)
// ---------------------------------------------------------------------------
__global__ __launch_bounds__(256) void xbf_kernel(
    const float* __restrict__ X, unsigned short* __restrict__ Xb, int n8)
{
    int i = blockIdx.x * 256 + threadIdx.x;
    const int stride = gridDim.x * 256;
    for (; i < n8; i += stride) {
        float4v a = *(const float4v*)(X + (size_t)i * 8);
        float4v b = *(const float4v*)(X + (size_t)i * 8 + 4);
        ushort8v o;
        #pragma unroll
        for (int j = 0; j < 4; ++j) { o[j] = f2bf(a[j]); o[4 + j] = f2bf(b[j]); }
        *(ushort8v*)(Xb + (size_t)i * 8) = o;
    }
}

// ---------------------------------------------------------------------------
// Kernel 1: Z[row][g*128+c] = bf16( Xb[row][:] @ Wg_x[:,c] + b ).  (unchanged)
// ---------------------------------------------------------------------------
__global__ __launch_bounds__(512, 4) void qlstm_xgemm(
    const unsigned short* __restrict__ Xb,   // [rows][128] bf16
    const float* __restrict__ Wf, const float* __restrict__ bfp,
    const float* __restrict__ Wi, const float* __restrict__ bip,
    const float* __restrict__ Wg, const float* __restrict__ bgp,
    const float* __restrict__ Wo, const float* __restrict__ bop,
    unsigned short* __restrict__ Z)
{
    const int tid = threadIdx.x, lane = tid & 63, wid = tid >> 6;
    const int l15 = lane & 15, kg = lane >> 4;
    const int g = wid >> 1;
    const float* Wsel = (g == 0) ? Wf : (g == 1) ? Wi : (g == 2) ? Wg : Wo;
    const float* bsel = (g == 0) ? bfp : (g == 1) ? bip : (g == 2) ? bgp : bop;
    const int cb  = (wid & 1) * 64;
    const int zcb = wid * 64;

    short8v aw[4][4];
    #pragma unroll
    for (int mt = 0; mt < 4; ++mt) {
        const int col = cb + mt * 16 + l15;
        #pragma unroll
        for (int ks = 0; ks < 4; ++ks) {
            const int k0 = ks * 32 + kg * 8;
            short8v a;
            #pragma unroll
            for (int j = 0; j < 8; ++j)
                a[j] = (short)f2bf(Wsel[(size_t)(k0 + j) * HID + col]);
            aw[mt][ks] = a;
        }
    }
    ushort4v biasb[4];
    #pragma unroll
    for (int mt = 0; mt < 4; ++mt)
        #pragma unroll
        for (int j = 0; j < 4; ++j)
            biasb[mt][j] = f2bf(bsel[cb + mt * 16 + kg * 4 + j]);

    const int rowbase = blockIdx.x * 128;

    short8v bx[4];
    {
        const unsigned short* xr = Xb + (size_t)(rowbase + l15) * HID;
        #pragma unroll
        for (int ks = 0; ks < 4; ++ks)
            bx[ks] = *(const short8v*)(xr + ks * 32 + kg * 8);
    }

    for (int rg = 0; rg < 8; ++rg) {
        float4v acc[4];
        #pragma unroll
        for (int mt = 0; mt < 4; ++mt)
            #pragma unroll
            for (int j = 0; j < 4; ++j) acc[mt][j] = bf2f(biasb[mt][j]);

        #pragma unroll
        for (int ks = 0; ks < 4; ++ks)
            #pragma unroll
            for (int mt = 0; mt < 4; ++mt)
                acc[mt] = __builtin_amdgcn_mfma_f32_16x16x32_bf16(aw[mt][ks], bx[ks], acc[mt], 0, 0, 0);

        if (rg < 7) {
            const unsigned short* xr = Xb + (size_t)(rowbase + (rg + 1) * 16 + l15) * HID;
            #pragma unroll
            for (int ks = 0; ks < 4; ++ks)
                bx[ks] = *(const short8v*)(xr + ks * 32 + kg * 8);
        }

        const size_t zr = (size_t)(rowbase + rg * 16 + l15) * GC + zcb;
        #pragma unroll
        for (int mt = 0; mt < 4; ++mt) {
            ushort4v o;
            #pragma unroll
            for (int j = 0; j < 4; ++j) o[j] = f2bf(acc[mt][j]);
            *(ushort4v*)&Z[zr + mt * 16 + kg * 4] = o;
        }
    }
}

// ---------------------------------------------------------------------------
// Kernel 2: recurrent. 256 WGs x 256 thr (4 waves), 2 batch rows in M-slots
// (A[m][k] = h_{m&1}[k]), 1 WG/CU.  ONE BARRIER PER STEP:
//   Phase A: wave g = gate g: 32 MFMA -> extract 2 cols x 2 rows -> +Z ->
//     activate own gate -> publish to parity-buffered gact[par].
//   BAR.
//   Phase B (ALL waves, redundant): read gact[par] (8 b64), per-row DPP
//     cumprod scan + cell update, EACH wave writes a complete identical
//     copy of h_bf[par^1] (both rows). Next step's A-frag read is then
//     satisfied by the wave's OWN write -> no second barrier. Parity
//     double-buffers bound the 1-step skew window (race-free).
//   wave0 additionally writes out / final state.
// ---------------------------------------------------------------------------
__global__ __launch_bounds__(256, 1) void qlstm_rec(
    const unsigned short* __restrict__ Z,   // [chunk][BATCH][GC] bf16
    const float* __restrict__ Wf, const float* __restrict__ Wi,
    const float* __restrict__ Wg, const float* __restrict__ Wo,
    float* __restrict__ out,
    unsigned short* __restrict__ hstate,    // bf16 [BATCH][HID]
    float* __restrict__ cstate,             // f32  [BATCH][HID]
    int t0, int chunk, int last)
{
    __shared__ float gact[2][2][4][HID];    // [parity][row][gate][col]; g0=cos(f)
    __shared__ alignas(16) unsigned short h_bf[2][2][HID];   // [parity][row][col]

    const int tid = threadIdx.x, lane = tid & 63, wid = tid >> 6;
    const int l15 = lane & 15, kg = lane >> 4;
    const int b0 = blockIdx.x * 2;          // batch rows b0, b0+1
    const float* Wsel = (wid == 0) ? Wf : (wid == 1) ? Wi : (wid == 2) ? Wg : Wo;

    // B-frags: bw[n][ks] = W[128 + ks*32 + kg*8 + j][n*16 + l15]   (128 VGPR)
    short8v bw[8][4];
    #pragma unroll
    for (int n = 0; n < 8; ++n) {
        const int col = n * 16 + l15;
        #pragma unroll
        for (int ks = 0; ks < 4; ++ks) {
            const int k0 = 128 + ks * 32 + kg * 8;
            short8v a;
            #pragma unroll
            for (int j = 0; j < 8; ++j)
                a[j] = (short)f2bf(Wsel[(size_t)(k0 + j) * HID + col]);
            bw[n][ks] = a;
        }
    }

    // h_bf[0] init: rows b0,b0+1 contiguous (256 ushorts = 128 dwords)
    if (tid < 128)
        ((unsigned*)&h_bf[0][0][0])[tid] =
            ((const unsigned*)(hstate + (size_t)b0 * HID))[tid];

    // cell state for cols {2*lane, 2*lane+1}, both rows (all waves, redundant)
    float c00, c01, c10, c11;
    {
        float2v cr0 = *(const float2v*)&cstate[(size_t)b0 * HID + 2 * lane];
        float2v cr1 = *(const float2v*)&cstate[(size_t)(b0 + 1) * HID + 2 * lane];
        c00 = cr0[0]; c01 = cr0[1]; c10 = cr1[0]; c11 = cr1[1];
    }
    float hL00 = 0.f, hL01 = 0.f, hL10 = 0.f, hL11 = 0.f;

    // this lane's activation cols (gate wid): ca0 = kg*32+l15, ca1 = ca0+16
    const int ca0 = kg * 32 + l15;
    unsigned short z00, z01, z10, z11;      // z[row][colpair]
    {
        const unsigned short* zb = Z + (size_t)b0 * GC + wid * HID;
        z00 = zb[ca0]; z01 = zb[ca0 + 16];
        z10 = zb[GC + ca0]; z11 = zb[GC + ca0 + 16];
    }

    BAR();

    for (int t = 0; t < chunk; ++t) {
        const int par = t & 1;

        // ---- Phase A: [2 rows] @ Wh (gate = wid), rows replicated in M ----
        short8v ah[4];                      // A[m=l15][k] = h_{l15&1}[k]
        #pragma unroll
        for (int ks = 0; ks < 4; ++ks)
            ah[ks] = *(const short8v*)&h_bf[par][l15 & 1][ks * 32 + kg * 8];

        float4v acc[8];
        #pragma unroll
        for (int n = 0; n < 8; ++n)
            #pragma unroll
            for (int j = 0; j < 4; ++j) acc[n][j] = 0.f;

        __builtin_amdgcn_s_setprio(1);
        #pragma unroll
        for (int ks = 0; ks < 4; ++ks)
            #pragma unroll
            for (int n = 0; n < 8; ++n)
                acc[n] = __builtin_amdgcn_mfma_f32_16x16x32_bf16(ah[ks], bw[n][ks], acc[n], 0, 0, 0);
        __builtin_amdgcn_s_setprio(0);

        // ---- extract: tiles n=2kg,2kg+1; reg parity = batch row ----
        float s0r0 = (kg == 0) ? acc[0][0] : (kg == 1) ? acc[2][0]
                   : (kg == 2) ? acc[4][0] : acc[6][0];
        float s0r1 = (kg == 0) ? acc[0][1] : (kg == 1) ? acc[2][1]
                   : (kg == 2) ? acc[4][1] : acc[6][1];
        float s1r0 = (kg == 0) ? acc[1][0] : (kg == 1) ? acc[3][0]
                   : (kg == 2) ? acc[5][0] : acc[7][0];
        float s1r1 = (kg == 0) ? acc[1][1] : (kg == 1) ? acc[3][1]
                   : (kg == 2) ? acc[5][1] : acc[7][1];
        s0r0 += bf2f(z00); s1r0 += bf2f(z01);
        s0r1 += bf2f(z10); s1r1 += bf2f(z11);

        {   // prefetch Z[t+1] (flies across the barrier)
            const int tn = (t + 1 < chunk) ? (t + 1) : t;
            const unsigned short* zb = Z + ((size_t)tn * BATCH + b0) * GC + wid * HID;
            z00 = zb[ca0]; z01 = zb[ca0 + 16];
            z10 = zb[GC + ca0]; z11 = zb[GC + ca0 + 16];
        }

        // ---- in-wave activation of own gate, both rows ----
        float v00, v01, v10, v11;
        if (wid == 0) {
            v00 = fast_cos(s0r0); v01 = fast_cos(s1r0);
            v10 = fast_cos(s0r1); v11 = fast_cos(s1r1);
        } else if (wid == 1) {
            v00 = (fast_cos(s0r0) + 1.f) * .5f; v01 = (fast_cos(s1r0) + 1.f) * .5f;
            v10 = (fast_cos(s0r1) + 1.f) * .5f; v11 = (fast_cos(s1r1) + 1.f) * .5f;
        } else if (wid == 2) {
            v00 = fast_tanh(s0r0); v01 = fast_tanh(s1r0);
            v10 = fast_tanh(s0r1); v11 = fast_tanh(s1r1);
        } else {
            v00 = fast_sigmoid(s0r0); v01 = fast_sigmoid(s1r0);
            v10 = fast_sigmoid(s0r1); v11 = fast_sigmoid(s1r1);
        }
        gact[par][0][wid][ca0]      = v00;
        gact[par][0][wid][ca0 + 16] = v01;
        gact[par][1][wid][ca0]      = v10;
        gact[par][1][wid][ca0 + 16] = v11;

        BAR();  // the ONLY barrier: gact[par] ready

        // ---- Phase B: ALL waves (redundant): scan + cell, both rows ----
        float2v fc0 = *(const float2v*)&gact[par][0][0][2 * lane];
        float2v iv0 = *(const float2v*)&gact[par][0][1][2 * lane];
        float2v gv0 = *(const float2v*)&gact[par][0][2][2 * lane];
        float2v ov0 = *(const float2v*)&gact[par][0][3][2 * lane];
        float2v fc1 = *(const float2v*)&gact[par][1][0][2 * lane];
        float2v iv1 = *(const float2v*)&gact[par][1][1][2 * lane];
        float2v gv1 = *(const float2v*)&gact[par][1][2][2 * lane];
        float2v ov1 = *(const float2v*)&gact[par][1][3][2 * lane];

        // row 0 scan
        const float pair0 = fc0[0] * fc0[1];
        float R0 = pair0;
        R0 *= dpp1<0x111, 0xf>(R0);
        R0 *= dpp1<0x112, 0xf>(R0);
        R0 *= dpp1<0x114, 0xf>(R0);
        R0 *= dpp1<0x118, 0xf>(R0);
        const float Er0 = dpp1<0x111, 0xf>(R0);
        // row 1 scan
        const float pair1 = fc1[0] * fc1[1];
        float R1 = pair1;
        R1 *= dpp1<0x111, 0xf>(R1);
        R1 *= dpp1<0x112, 0xf>(R1);
        R1 *= dpp1<0x114, 0xf>(R1);
        R1 *= dpp1<0x118, 0xf>(R1);
        const float Er1 = dpp1<0x111, 0xf>(R1);

        const float T00 = __shfl(R0, 15), T01 = __shfl(R0, 31), T02 = __shfl(R0, 47);
        const float T10 = __shfl(R1, 15), T11 = __shfl(R1, 31), T12 = __shfl(R1, 47);
        const float rp0 = (kg == 0) ? 1.f : (kg == 1) ? T00
                        : (kg == 2) ? T00 * T01 : T00 * T01 * T02;
        const float rp1 = (kg == 0) ? 1.f : (kg == 1) ? T10
                        : (kg == 2) ? T10 * T11 : T10 * T11 * T12;
        const float E0 = Er0 * rp0;
        const float E1 = Er1 * rp1;

        const float f00 = (E0 * fc0[0] + 1.f) * 0.5f;
        const float f01 = (E0 * pair0 + 1.f) * 0.5f;
        const float f10 = (E1 * fc1[0] + 1.f) * 0.5f;
        const float f11 = (E1 * pair1 + 1.f) * 0.5f;

        const float cn00 = fmaf(f00, c00, iv0[0] * gv0[0]);
        const float cn01 = fmaf(f01, c01, iv0[1] * gv0[1]);
        const float cn10 = fmaf(f10, c10, iv1[0] * gv1[0]);
        const float cn11 = fmaf(f11, c11, iv1[1] * gv1[1]);
        const float hn00 = ov0[0] * fast_tanh(cn00);
        const float hn01 = ov0[1] * fast_tanh(cn01);
        const float hn10 = ov1[0] * fast_tanh(cn10);
        const float hn11 = ov1[1] * fast_tanh(cn11);
        c00 = cn00; c01 = cn01; c10 = cn10; c11 = cn11;
        hL00 = hn00; hL01 = hn01; hL10 = hn10; hL11 = hn11;

        // every wave writes the FULL h (both rows) -> self-satisfies next read
        *(unsigned*)&h_bf[par ^ 1][0][2 * lane] =
            (unsigned)f2bf(hn00) | ((unsigned)f2bf(hn01) << 16);
        *(unsigned*)&h_bf[par ^ 1][1][2 * lane] =
            (unsigned)f2bf(hn10) | ((unsigned)f2bf(hn11) << 16);

        if (wid == 0) {
            float2v o20; o20[0] = hn00; o20[1] = hn01;
            float2v o21; o21[0] = hn10; o21[1] = hn11;
            *(float2v*)&out[((size_t)(t0 + t) * BATCH + b0) * HID + 2 * lane] = o20;
            *(float2v*)&out[((size_t)(t0 + t) * BATCH + b0 + 1) * HID + 2 * lane] = o21;
        }
        // no second barrier (see header comment)
    }

    // save state; final hx/cx tails (wave 0)
    if (wid == 0) {
        const size_t r0 = (size_t)b0 * HID + 2 * lane;
        const size_t r1 = (size_t)(b0 + 1) * HID + 2 * lane;
        hstate[r0] = f2bf(hL00); hstate[r0 + 1] = f2bf(hL01);
        hstate[r1] = f2bf(hL10); hstate[r1 + 1] = f2bf(hL11);
        float2v cs0; cs0[0] = c00; cs0[1] = c01;
        float2v cs1; cs1[0] = c10; cs1[1] = c11;
        *(float2v*)&cstate[r0] = cs0;
        *(float2v*)&cstate[r1] = cs1;
        if (last) {
            const size_t base = (size_t)SEQ * BATCH * HID;
            float2v h20; h20[0] = hL00; h20[1] = hL01;
            float2v h21; h21[0] = hL10; h21[1] = hL11;
            *(float2v*)&out[base + r0] = h20;
            *(float2v*)&out[base + r1] = h21;
            *(float2v*)&out[base + (size_t)BATCH * HID + r0] = cs0;
            *(float2v*)&out[base + (size_t)BATCH * HID + r1] = cs1;
        }
    }
}

// ---------------------------------------------------------------------------
extern "C" void kernel_launch(void* const* d_in, const int* in_sizes, int n_in,
                              void* d_out, int out_size, void* d_ws, size_t ws_size,
                              hipStream_t stream) {
    const float* X  = (const float*)d_in[0];
    const float* Wf = (const float*)d_in[1];
    const float* bf = (const float*)d_in[2];
    const float* Wi = (const float*)d_in[3];
    const float* bi = (const float*)d_in[4];
    const float* Wg = (const float*)d_in[5];
    const float* bg = (const float*)d_in[6];
    const float* Wo = (const float*)d_in[7];
    const float* bo = (const float*)d_in[8];
    float* out = (float*)d_out;

    char* ws = (char*)d_ws;
    unsigned short* hstate = (unsigned short*)ws;                 // 128 KB used
    float*          cstate = (float*)(ws + 256 * 1024);           // 256 KB
    char*           dynws  = ws + 1024 * 1024;

    const size_t xstep = (size_t)BATCH * HID * sizeof(unsigned short);  // 128 KB
    const size_t zstep = (size_t)BATCH * GC  * sizeof(unsigned short);  // 512 KB
    size_t cap = (ws_size > (1u << 20)) ? ws_size - (1u << 20) : 0;
    int Tc = (int)(cap / (xstep + zstep));
    if (Tc > SEQ) Tc = SEQ;
    if (Tc < 1)   Tc = 1;

    hipMemsetAsync(ws, 0, 1024 * 1024, stream);   // zero h/c state

    for (int t0 = 0; t0 < SEQ; t0 += Tc) {
        const int chunk = (SEQ - t0 < Tc) ? (SEQ - t0) : Tc;
        unsigned short* Xbf  = (unsigned short*)dynws;
        unsigned short* Zbuf = (unsigned short*)(dynws + (size_t)chunk * xstep);

        const int n8 = chunk * BATCH * HID / 8;
        xbf_kernel<<<2048, 256, 0, stream>>>(
            X + (size_t)t0 * BATCH * HID, Xbf, n8);
        qlstm_xgemm<<<chunk * BATCH / 128, 512, 0, stream>>>(
            Xbf, Wf, bf, Wi, bi, Wg, bg, Wo, bo, Zbuf);
        qlstm_rec<<<BATCH / 2, 256, 0, stream>>>(
            Zbuf, Wf, Wi, Wg, Wo, out, hstate, cstate,
            t0, chunk, (t0 + chunk == SEQ) ? 1 : 0);
    }
}

// Round 11
// 1209.449 us; speedup vs baseline: 1.3834x; 1.3834x over previous
//
#include <hip/hip_runtime.h>

#define SEQ   1024
#define BATCH 512
#define HID   128

typedef __attribute__((ext_vector_type(8))) short  short8v;
typedef __attribute__((ext_vector_type(4))) float  float4v;
typedef __attribute__((ext_vector_type(2))) float  float2v;

__device__ __forceinline__ unsigned short f2bf(float f) {
    union { float f; unsigned u; } v; v.f = f;
    return (unsigned short)((v.u + 0x7fffu + ((v.u >> 16) & 1u)) >> 16);
}
__device__ __forceinline__ float fast_cos(float x) {
    return __builtin_amdgcn_cosf(x * 0.15915494309189535f);   // v_cos takes revolutions
}
__device__ __forceinline__ float fast_sigmoid(float x) {
    return __builtin_amdgcn_rcpf(1.0f + __builtin_amdgcn_exp2f(-1.4426950408889634f * x));
}
__device__ __forceinline__ float fast_tanh(float x) {
    return 1.0f - 2.0f * __builtin_amdgcn_rcpf(1.0f + __builtin_amdgcn_exp2f(2.8853900817779268f * x));
}
// DPP helper: returns src shifted by CTRL, invalid/masked lanes get 1.0f
template<int CTRL, int RM>
__device__ __forceinline__ float dpp1(float v) {
    union { float f; int i; } s, o, r;
    s.f = v; o.f = 1.0f;
    r.i = __builtin_amdgcn_update_dpp(o.i, s.i, CTRL, RM, 0xf, false);
    return r.f;
}
// raw barrier: drains LDS only; global loads stay in flight across it
#define BAR() do { asm volatile("s_waitcnt lgkmcnt(0)" ::: "memory");  \
                   __builtin_amdgcn_s_barrier();                       \
                   __builtin_amdgcn_sched_barrier(0); } while (0)

// ---------------------------------------------------------------------------
// ONE persistent kernel. 256 WGs x 512 thr (8 waves), 2 batch rows/WG, 1 WG/CU.
// Waves 0-3 = CONSUMERS (gate wid): R9 recurrence — A = h rows replicated in
//   M-slots, B = W_h frags in regs, z added from LDS ring.
// Waves 4-7 = PRODUCERS (gate wid-4): x-GEMM for step t+4 — A = x rows
//   replicated in M-slots (from x_bf LDS, staged by wave 4 with a 1-step
//   register prefetch), B = W_x frags in regs, bias in acc init. Output goes
//   to zring[(t+4)%8][gate][col][row] (f32) — NO global Z, no xbf/xgemm
//   kernels, no chunk loop, no workspace at all.
// Ring safety: slot s written in Phase B of step s-4, read in Phase A of
// step s (>=7 barriers apart). x_bf: written Phase A(t), read Phase B(t),
// rewritten Phase A(t+1) — S1/S2 separate every pair.
// Per step: Phase A = consumer MFMA+act (producers just stage x);
//           S1; Phase B = producer MFMA+ring-write overlapping worker
//           scan+cell (different waves, different pipes, same SIMD); S2.
// ---------------------------------------------------------------------------
__global__ __launch_bounds__(512, 1) void qlstm_fused(
    const float* __restrict__ X,
    const float* __restrict__ Wf, const float* __restrict__ bfp,
    const float* __restrict__ Wi, const float* __restrict__ bip,
    const float* __restrict__ Wg, const float* __restrict__ bgp,
    const float* __restrict__ Wo, const float* __restrict__ bop,
    float* __restrict__ out)
{
    __shared__ alignas(16) float zring[8][4][HID][2];   // [slot][gate][col][row] 32 KB
    __shared__ alignas(16) float gact[2][4][HID];       // [row][gate][col]; g0 = cos(f)
    __shared__ alignas(8)  unsigned short h_bf[2][HID];
    __shared__ alignas(8)  unsigned short x_bf[2][HID];

    const int tid = threadIdx.x, lane = tid & 63, wid = tid >> 6;
    const int l15 = lane & 15, kg = lane >> 4;
    const int b0 = blockIdx.x * 2;          // batch rows b0, b0+1
    const bool prod = (wid >= 4);
    const int g = wid & 3;
    const float* Wsel = (g == 0) ? Wf : (g == 1) ? Wi : (g == 2) ? Wg : Wo;
    const float* bsel = (g == 0) ? bfp : (g == 1) ? bip : (g == 2) ? bgp : bop;

    // shared-role weight fragments: consumers k=128..255 (W_h), producers k=0..127 (W_x)
    short8v bw[8][4];
    {
        const int kbase = prod ? 0 : 128;
        #pragma unroll
        for (int n = 0; n < 8; ++n) {
            const int col = n * 16 + l15;
            #pragma unroll
            for (int ks = 0; ks < 4; ++ks) {
                const int k0 = kbase + ks * 32 + kg * 8;
                short8v a;
                #pragma unroll
                for (int j = 0; j < 8; ++j)
                    a[j] = (short)f2bf(Wsel[(size_t)(k0 + j) * HID + col]);
                bw[n][ks] = a;
            }
        }
    }
    float biasr[8];
    #pragma unroll
    for (int n = 0; n < 8; ++n) biasr[n] = prod ? bsel[n * 16 + l15] : 0.f;

    if (tid < 128) ((unsigned*)h_bf)[tid] = 0u;   // h0 = 0

    const bool worker = !prod && ((wid >> 1) == (blockIdx.x & 1));  // 2 waves, SIMD-staggered
    const int wrow = wid & 1;
    float c0 = 0.f, c1 = 0.f, hL0 = 0.f, hL1 = 0.f;   // c0 = 0
    const int ca0 = kg * 32 + l15;

    // ---- prologue: produce zring slots 0..3 (not perf-critical) ----
    #pragma unroll 1
    for (int p = 0; p < 4; ++p) {
        if (wid == 4) {
            float4v xv = *(const float4v*)(X + ((size_t)p * BATCH + b0) * HID + lane * 4);
            unsigned* dst = (unsigned*)&x_bf[lane >> 5][(lane & 31) * 4];
            dst[0] = (unsigned)f2bf(xv[0]) | ((unsigned)f2bf(xv[1]) << 16);
            dst[1] = (unsigned)f2bf(xv[2]) | ((unsigned)f2bf(xv[3]) << 16);
        }
        BAR();
        if (prod) {
            short8v ax[4];
            #pragma unroll
            for (int ks = 0; ks < 4; ++ks)
                ax[ks] = *(const short8v*)&x_bf[l15 & 1][ks * 32 + kg * 8];
            float4v acc[8];
            #pragma unroll
            for (int n = 0; n < 8; ++n)
                #pragma unroll
                for (int j = 0; j < 4; ++j) acc[n][j] = biasr[n];
            #pragma unroll
            for (int ks = 0; ks < 4; ++ks)
                #pragma unroll
                for (int n = 0; n < 8; ++n)
                    acc[n] = __builtin_amdgcn_mfma_f32_16x16x32_bf16(ax[ks], bw[n][ks], acc[n], 0, 0, 0);
            if (kg == 0) {
                #pragma unroll
                for (int n = 0; n < 8; ++n) {
                    float2v zz; zz[0] = acc[n][0]; zz[1] = acc[n][1];
                    *(float2v*)&zring[p][g][n * 16 + l15][0] = zz;
                }
            }
        }
        BAR();
    }

    float4v xv;   // wave-4 register prefetch of x[t+4]
    if (wid == 4) xv = *(const float4v*)(X + ((size_t)4 * BATCH + b0) * HID + lane * 4);

    for (int t = 0; t < SEQ; ++t) {
        const int slot = t & 7;

        // ---------------- Phase A ----------------
        if (!prod) {
            // consumer: preact = zring[t] + h @ W_h  (rows replicated in M)
            short8v ah[4];
            #pragma unroll
            for (int ks = 0; ks < 4; ++ks)
                ah[ks] = *(const short8v*)&h_bf[l15 & 1][ks * 32 + kg * 8];

            float4v acc[8];
            #pragma unroll
            for (int n = 0; n < 8; ++n)
                #pragma unroll
                for (int j = 0; j < 4; ++j) acc[n][j] = 0.f;

            __builtin_amdgcn_s_setprio(1);
            #pragma unroll
            for (int ks = 0; ks < 4; ++ks)
                #pragma unroll
                for (int n = 0; n < 8; ++n)
                    acc[n] = __builtin_amdgcn_mfma_f32_16x16x32_bf16(ah[ks], bw[n][ks], acc[n], 0, 0, 0);
            __builtin_amdgcn_s_setprio(0);

            float2v zr0 = *(const float2v*)&zring[slot][g][ca0][0];
            float2v zr1 = *(const float2v*)&zring[slot][g][ca0 + 16][0];

            // tiles n=2kg,2kg+1; reg parity = batch row
            float s0r0 = (kg == 0) ? acc[0][0] : (kg == 1) ? acc[2][0]
                       : (kg == 2) ? acc[4][0] : acc[6][0];
            float s0r1 = (kg == 0) ? acc[0][1] : (kg == 1) ? acc[2][1]
                       : (kg == 2) ? acc[4][1] : acc[6][1];
            float s1r0 = (kg == 0) ? acc[1][0] : (kg == 1) ? acc[3][0]
                       : (kg == 2) ? acc[5][0] : acc[7][0];
            float s1r1 = (kg == 0) ? acc[1][1] : (kg == 1) ? acc[3][1]
                       : (kg == 2) ? acc[5][1] : acc[7][1];
            s0r0 += zr0[0]; s0r1 += zr0[1];
            s1r0 += zr1[0]; s1r1 += zr1[1];

            float v00, v01, v10, v11;
            if (g == 0) {
                v00 = fast_cos(s0r0); v01 = fast_cos(s1r0);
                v10 = fast_cos(s0r1); v11 = fast_cos(s1r1);
            } else if (g == 1) {
                v00 = (fast_cos(s0r0) + 1.f) * .5f; v01 = (fast_cos(s1r0) + 1.f) * .5f;
                v10 = (fast_cos(s0r1) + 1.f) * .5f; v11 = (fast_cos(s1r1) + 1.f) * .5f;
            } else if (g == 2) {
                v00 = fast_tanh(s0r0); v01 = fast_tanh(s1r0);
                v10 = fast_tanh(s0r1); v11 = fast_tanh(s1r1);
            } else {
                v00 = fast_sigmoid(s0r0); v01 = fast_sigmoid(s1r0);
                v10 = fast_sigmoid(s0r1); v11 = fast_sigmoid(s1r1);
            }
            gact[0][g][ca0]      = v00;
            gact[0][g][ca0 + 16] = v01;
            gact[1][g][ca0]      = v10;
            gact[1][g][ca0 + 16] = v11;
        } else if (wid == 4 && t + 4 < SEQ) {
            // publish x[t+4] (prefetched last step), start prefetch of x[t+5]
            unsigned* dst = (unsigned*)&x_bf[lane >> 5][(lane & 31) * 4];
            dst[0] = (unsigned)f2bf(xv[0]) | ((unsigned)f2bf(xv[1]) << 16);
            dst[1] = (unsigned)f2bf(xv[2]) | ((unsigned)f2bf(xv[3]) << 16);
            if (t + 5 < SEQ)
                xv = *(const float4v*)(X + ((size_t)(t + 5) * BATCH + b0) * HID + lane * 4);
        }
        BAR();  // S1: gact + x_bf ready

        // ---------------- Phase B ----------------
        if (prod) {
            if (t + 4 < SEQ) {
                // x-GEMM for step t+4 into zring[(t+4)%8]; overlaps worker scan
                short8v ax[4];
                #pragma unroll
                for (int ks = 0; ks < 4; ++ks)
                    ax[ks] = *(const short8v*)&x_bf[l15 & 1][ks * 32 + kg * 8];
                float4v acc[8];
                #pragma unroll
                for (int n = 0; n < 8; ++n)
                    #pragma unroll
                    for (int j = 0; j < 4; ++j) acc[n][j] = biasr[n];
                __builtin_amdgcn_s_setprio(1);
                #pragma unroll
                for (int ks = 0; ks < 4; ++ks)
                    #pragma unroll
                    for (int n = 0; n < 8; ++n)
                        acc[n] = __builtin_amdgcn_mfma_f32_16x16x32_bf16(ax[ks], bw[n][ks], acc[n], 0, 0, 0);
                __builtin_amdgcn_s_setprio(0);
                if (kg == 0) {
                    const int sp = (t + 4) & 7;
                    #pragma unroll
                    for (int n = 0; n < 8; ++n) {
                        float2v zz; zz[0] = acc[n][0]; zz[1] = acc[n][1];
                        *(float2v*)&zring[sp][g][n * 16 + l15][0] = zz;
                    }
                }
            }
        } else if (worker) {
            // scan + cell for row wrow, cols {2*lane, 2*lane+1}
            float2v fc = *(const float2v*)&gact[wrow][0][2 * lane];
            float2v iv = *(const float2v*)&gact[wrow][1][2 * lane];
            float2v gv = *(const float2v*)&gact[wrow][2][2 * lane];
            float2v ov = *(const float2v*)&gact[wrow][3][2 * lane];

            const float pair = fc[0] * fc[1];
            float R = pair;
            R *= dpp1<0x111, 0xf>(R);       // row_shr:1
            R *= dpp1<0x112, 0xf>(R);       // row_shr:2
            R *= dpp1<0x114, 0xf>(R);       // row_shr:4
            R *= dpp1<0x118, 0xf>(R);       // row_shr:8  (16-lane incl scan)
            const float Erow = dpp1<0x111, 0xf>(R);
            const float T0 = __shfl(R, 15);
            const float T1 = __shfl(R, 31);
            const float T2 = __shfl(R, 47);
            const float rp = (kg == 0) ? 1.f : (kg == 1) ? T0
                           : (kg == 2) ? T0 * T1 : T0 * T1 * T2;
            const float E  = Erow * rp;                      // exclusive prefix
            const float f0 = (E * fc[0] + 1.f) * 0.5f;
            const float f1 = (E * pair  + 1.f) * 0.5f;

            const float cn0 = fmaf(f0, c0, iv[0] * gv[0]);
            const float cn1 = fmaf(f1, c1, iv[1] * gv[1]);
            const float hn0 = ov[0] * fast_tanh(cn0);
            const float hn1 = ov[1] * fast_tanh(cn1);
            c0 = cn0; c1 = cn1; hL0 = hn0; hL1 = hn1;

            *(unsigned*)&h_bf[wrow][2 * lane] =
                (unsigned)f2bf(hn0) | ((unsigned)f2bf(hn1) << 16);
            float2v o2; o2[0] = hn0; o2[1] = hn1;
            *(float2v*)&out[((size_t)t * BATCH + b0 + wrow) * HID + 2 * lane] = o2;
        }
        BAR();  // S2: h_bf (and next zring slot) ready
    }

    // final hx/cx tails (workers hold last-step values)
    if (worker) {
        const size_t base = (size_t)SEQ * BATCH * HID;
        const size_t ro = (size_t)(b0 + wrow) * HID + 2 * lane;
        float2v h2, c2;
        h2[0] = hL0; h2[1] = hL1; c2[0] = c0; c2[1] = c1;
        *(float2v*)&out[base + ro] = h2;
        *(float2v*)&out[base + (size_t)BATCH * HID + ro] = c2;
    }
}

// ---------------------------------------------------------------------------
extern "C" void kernel_launch(void* const* d_in, const int* in_sizes, int n_in,
                              void* d_out, int out_size, void* d_ws, size_t ws_size,
                              hipStream_t stream) {
    const float* X  = (const float*)d_in[0];
    const float* Wf = (const float*)d_in[1];
    const float* bf = (const float*)d_in[2];
    const float* Wi = (const float*)d_in[3];
    const float* bi = (const float*)d_in[4];
    const float* Wg = (const float*)d_in[5];
    const float* bg = (const float*)d_in[6];
    const float* Wo = (const float*)d_in[7];
    const float* bo = (const float*)d_in[8];
    float* out = (float*)d_out;
    (void)d_ws; (void)ws_size;   // no workspace needed: Z lives in LDS ring

    qlstm_fused<<<BATCH / 2, 512, 0, stream>>>(
        X, Wf, bf, Wi, bi, Wg, bg, Wo, bo, out);
}

// Round 12
// 1111.129 us; speedup vs baseline: 1.5058x; 1.0885x over previous
//
#include <hip/hip_runtime.h>

#define SEQ   1024
#define BATCH 512
#define HID   128

typedef __attribute__((ext_vector_type(8))) short  short8v;
typedef __attribute__((ext_vector_type(4))) float  float4v;
typedef __attribute__((ext_vector_type(2))) float  float2v;

__device__ __forceinline__ unsigned short f2bf(float f) {
    union { float f; unsigned u; } v; v.f = f;
    return (unsigned short)((v.u + 0x7fffu + ((v.u >> 16) & 1u)) >> 16);
}
__device__ __forceinline__ float fast_cos(float x) {
    return __builtin_amdgcn_cosf(x * 0.15915494309189535f);   // v_cos takes revolutions
}
__device__ __forceinline__ float fast_sigmoid(float x) {
    return __builtin_amdgcn_rcpf(1.0f + __builtin_amdgcn_exp2f(-1.4426950408889634f * x));
}
__device__ __forceinline__ float fast_tanh(float x) {
    return 1.0f - 2.0f * __builtin_amdgcn_rcpf(1.0f + __builtin_amdgcn_exp2f(2.8853900817779268f * x));
}
// DPP helper: returns src shifted by CTRL within 16-lane rows, masked lanes get 1.0f
template<int CTRL, int RM>
__device__ __forceinline__ float dpp1(float v) {
    union { float f; int i; } s, o, r;
    s.f = v; o.f = 1.0f;
    r.i = __builtin_amdgcn_update_dpp(o.i, s.i, CTRL, RM, 0xf, false);
    return r.f;
}
// raw barrier: drains LDS only; global loads/stores stay in flight across it
#define BAR() do { asm volatile("s_waitcnt lgkmcnt(0)" ::: "memory");  \
                   __builtin_amdgcn_s_barrier();                       \
                   __builtin_amdgcn_sched_barrier(0); } while (0)

// in-wave inclusive cumprod over 128 cols held as (a = col kg*32+l15,
// b = col kg*32+16+l15). 16-lane DPP scans + block totals via shfl.
__device__ __forceinline__ void fscan(float a, float b, int kg,
                                      float& Fa, float& Fb) {
    float Sa = a, Sb = b;
    Sa *= dpp1<0x111, 0xf>(Sa);  Sb *= dpp1<0x111, 0xf>(Sb);   // row_shr:1
    Sa *= dpp1<0x112, 0xf>(Sa);  Sb *= dpp1<0x112, 0xf>(Sb);   // row_shr:2
    Sa *= dpp1<0x114, 0xf>(Sa);  Sb *= dpp1<0x114, 0xf>(Sb);   // row_shr:4
    Sa *= dpp1<0x118, 0xf>(Sa);  Sb *= dpp1<0x118, 0xf>(Sb);   // row_shr:8
    const float T0a = __shfl(Sa, 15), T0b = __shfl(Sb, 15);
    const float T1a = __shfl(Sa, 31), T1b = __shfl(Sb, 31);
    const float T2a = __shfl(Sa, 47), T2b = __shfl(Sb, 47);
    const float Taown = __shfl(Sa, kg * 16 + 15);              // own-row a-total
    const float p0 = T0a * T0b, p1 = T1a * T1b, p2 = T2a * T2b;
    const float rp = (kg == 0) ? 1.f : (kg == 1) ? p0
                   : (kg == 2) ? p0 * p1 : p0 * p1 * p2;       // block prefix
    Fa = rp * Sa;                 // inclusive cumprod at col kg*32+l15
    Fb = rp * Taown * Sb;         // inclusive cumprod at col kg*32+16+l15
}

// ---------------------------------------------------------------------------
// ONE persistent kernel. 256 WGs x 512 thr (8 waves), 2 batch rows/WG, 1 WG/CU.
// Waves 0-3 = CONSUMERS (gate g=wid): recurrence MFMA (h rows replicated in
//   M-slots, W_h frags in regs, z from LDS ring) + in-register activation.
//   Wave 0 additionally does the FULL f-cumprod scan in-wave (fscan) and
//   publishes final f values.
// Waves 4-7 = PRODUCERS (gate g=wid-4): x-GEMM for step t+4, ALSO IN PHASE A
//   (shares the matrix pipe with consumer MFMA; slot read 8 barriers later).
//   No setprio for producers — Phase A's critical path is the consumer chain.
// Phase B: waves 0-3 cell update, 1 (row,col)/lane — no scan, ~4 LDS reads +
//   fma + tanh + h/out write. Wave 4 stages x[t+5] into x_bf (single buffer,
//   write after S1, read before next S1).
// ---------------------------------------------------------------------------
__global__ __launch_bounds__(512, 1) void qlstm_fused(
    const float* __restrict__ X,
    const float* __restrict__ Wf, const float* __restrict__ bfp,
    const float* __restrict__ Wi, const float* __restrict__ bip,
    const float* __restrict__ Wg, const float* __restrict__ bgp,
    const float* __restrict__ Wo, const float* __restrict__ bop,
    float* __restrict__ out)
{
    __shared__ alignas(16) float zring[8][4][HID][2];   // [slot][gate][col][row] 32 KB
    __shared__ alignas(16) float gact[2][4][HID];       // [row][gate][col]; g0 = FINAL f
    __shared__ alignas(8)  unsigned short h_bf[2][HID];
    __shared__ alignas(8)  unsigned short x_bf[2][HID];

    const int tid = threadIdx.x, lane = tid & 63, wid = tid >> 6;
    const int l15 = lane & 15, kg = lane >> 4;
    const int b0 = blockIdx.x * 2;          // batch rows b0, b0+1
    const bool prod = (wid >= 4);
    const int g = wid & 3;
    const float* Wsel = (g == 0) ? Wf : (g == 1) ? Wi : (g == 2) ? Wg : Wo;
    const float* bsel = (g == 0) ? bfp : (g == 1) ? bip : (g == 2) ? bgp : bop;

    // weight frags: consumers k=128..255 (W_h), producers k=0..127 (W_x)
    short8v bw[8][4];
    {
        const int kbase = prod ? 0 : 128;
        #pragma unroll
        for (int n = 0; n < 8; ++n) {
            const int col = n * 16 + l15;
            #pragma unroll
            for (int ks = 0; ks < 4; ++ks) {
                const int k0 = kbase + ks * 32 + kg * 8;
                short8v a;
                #pragma unroll
                for (int j = 0; j < 8; ++j)
                    a[j] = (short)f2bf(Wsel[(size_t)(k0 + j) * HID + col]);
                bw[n][ks] = a;
            }
        }
    }
    float biasr[8];
    #pragma unroll
    for (int n = 0; n < 8; ++n) biasr[n] = prod ? bsel[n * 16 + l15] : 0.f;

    if (tid < 128) ((unsigned*)h_bf)[tid] = 0u;   // h0 = 0

    // Phase-B cell state: waves 0-3, 1 (row,col) per lane
    const int crow = wid >> 1;                   // valid for wid<4
    const int ccol = (wid & 1) * 64 + lane;
    float c_reg = 0.f, h_last = 0.f;
    const int ca0 = kg * 32 + l15;

    // ---- prologue: produce zring slots 0..3; stage x[4]; prefetch x[5] ----
    #pragma unroll 1
    for (int p = 0; p < 4; ++p) {
        if (wid == 4) {
            float4v xv0 = *(const float4v*)(X + ((size_t)p * BATCH + b0) * HID + lane * 4);
            unsigned* dst = (unsigned*)&x_bf[lane >> 5][(lane & 31) * 4];
            dst[0] = (unsigned)f2bf(xv0[0]) | ((unsigned)f2bf(xv0[1]) << 16);
            dst[1] = (unsigned)f2bf(xv0[2]) | ((unsigned)f2bf(xv0[3]) << 16);
        }
        BAR();
        if (prod) {
            short8v ax[4];
            #pragma unroll
            for (int ks = 0; ks < 4; ++ks)
                ax[ks] = *(const short8v*)&x_bf[l15 & 1][ks * 32 + kg * 8];
            float4v acc[8];
            #pragma unroll
            for (int n = 0; n < 8; ++n)
                #pragma unroll
                for (int j = 0; j < 4; ++j) acc[n][j] = biasr[n];
            #pragma unroll
            for (int ks = 0; ks < 4; ++ks)
                #pragma unroll
                for (int n = 0; n < 8; ++n)
                    acc[n] = __builtin_amdgcn_mfma_f32_16x16x32_bf16(ax[ks], bw[n][ks], acc[n], 0, 0, 0);
            if (kg == 0) {
                #pragma unroll
                for (int n = 0; n < 8; ++n) {
                    float2v zz; zz[0] = acc[n][0]; zz[1] = acc[n][1];
                    *(float2v*)&zring[p][g][n * 16 + l15][0] = zz;
                }
            }
        }
        BAR();
    }
    if (wid == 4) {
        float4v xv0 = *(const float4v*)(X + ((size_t)4 * BATCH + b0) * HID + lane * 4);
        unsigned* dst = (unsigned*)&x_bf[lane >> 5][(lane & 31) * 4];
        dst[0] = (unsigned)f2bf(xv0[0]) | ((unsigned)f2bf(xv0[1]) << 16);
        dst[1] = (unsigned)f2bf(xv0[2]) | ((unsigned)f2bf(xv0[3]) << 16);
    }
    BAR();
    float4v xv;   // wave-4 register prefetch
    if (wid == 4) xv = *(const float4v*)(X + ((size_t)5 * BATCH + b0) * HID + lane * 4);

    for (int t = 0; t < SEQ; ++t) {
        const int slot = t & 7;

        // ---------------- Phase A ----------------
        if (!prod) {
            // consumer: preact = zring[t] + h @ W_h (rows replicated in M)
            short8v ah[4];
            #pragma unroll
            for (int ks = 0; ks < 4; ++ks)
                ah[ks] = *(const short8v*)&h_bf[l15 & 1][ks * 32 + kg * 8];

            float4v acc[8];
            #pragma unroll
            for (int n = 0; n < 8; ++n)
                #pragma unroll
                for (int j = 0; j < 4; ++j) acc[n][j] = 0.f;

            __builtin_amdgcn_s_setprio(1);
            #pragma unroll
            for (int ks = 0; ks < 4; ++ks)
                #pragma unroll
                for (int n = 0; n < 8; ++n)
                    acc[n] = __builtin_amdgcn_mfma_f32_16x16x32_bf16(ah[ks], bw[n][ks], acc[n], 0, 0, 0);
            __builtin_amdgcn_s_setprio(0);

            float2v zr0 = *(const float2v*)&zring[slot][g][ca0][0];
            float2v zr1 = *(const float2v*)&zring[slot][g][ca0 + 16][0];

            // tiles n=2kg,2kg+1; reg parity = batch row
            float s0r0 = (kg == 0) ? acc[0][0] : (kg == 1) ? acc[2][0]
                       : (kg == 2) ? acc[4][0] : acc[6][0];
            float s0r1 = (kg == 0) ? acc[0][1] : (kg == 1) ? acc[2][1]
                       : (kg == 2) ? acc[4][1] : acc[6][1];
            float s1r0 = (kg == 0) ? acc[1][0] : (kg == 1) ? acc[3][0]
                       : (kg == 2) ? acc[5][0] : acc[7][0];
            float s1r1 = (kg == 0) ? acc[1][1] : (kg == 1) ? acc[3][1]
                       : (kg == 2) ? acc[5][1] : acc[7][1];
            s0r0 += zr0[0]; s0r1 += zr0[1];
            s1r0 += zr1[0]; s1r1 += zr1[1];

            float v00, v01, v10, v11;
            if (g == 0) {
                // cos + full in-wave cumprod scan -> FINAL f values
                float Fa0, Fb0, Fa1, Fb1;
                fscan(fast_cos(s0r0), fast_cos(s1r0), kg, Fa0, Fb0);
                fscan(fast_cos(s0r1), fast_cos(s1r1), kg, Fa1, Fb1);
                v00 = (Fa0 + 1.f) * 0.5f; v01 = (Fb0 + 1.f) * 0.5f;
                v10 = (Fa1 + 1.f) * 0.5f; v11 = (Fb1 + 1.f) * 0.5f;
            } else if (g == 1) {
                v00 = (fast_cos(s0r0) + 1.f) * .5f; v01 = (fast_cos(s1r0) + 1.f) * .5f;
                v10 = (fast_cos(s0r1) + 1.f) * .5f; v11 = (fast_cos(s1r1) + 1.f) * .5f;
            } else if (g == 2) {
                v00 = fast_tanh(s0r0); v01 = fast_tanh(s1r0);
                v10 = fast_tanh(s0r1); v11 = fast_tanh(s1r1);
            } else {
                v00 = fast_sigmoid(s0r0); v01 = fast_sigmoid(s1r0);
                v10 = fast_sigmoid(s0r1); v11 = fast_sigmoid(s1r1);
            }
            gact[0][g][ca0]      = v00;
            gact[0][g][ca0 + 16] = v01;
            gact[1][g][ca0]      = v10;
            gact[1][g][ca0 + 16] = v11;
        } else if (t + 4 < SEQ) {
            // producer: x-GEMM for slot t+4 (read 8 barriers later). NO setprio.
            short8v ax[4];
            #pragma unroll
            for (int ks = 0; ks < 4; ++ks)
                ax[ks] = *(const short8v*)&x_bf[l15 & 1][ks * 32 + kg * 8];
            float4v acc[8];
            #pragma unroll
            for (int n = 0; n < 8; ++n)
                #pragma unroll
                for (int j = 0; j < 4; ++j) acc[n][j] = biasr[n];
            #pragma unroll
            for (int ks = 0; ks < 4; ++ks)
                #pragma unroll
                for (int n = 0; n < 8; ++n)
                    acc[n] = __builtin_amdgcn_mfma_f32_16x16x32_bf16(ax[ks], bw[n][ks], acc[n], 0, 0, 0);
            if (kg == 0) {
                const int sp = (t + 4) & 7;
                #pragma unroll
                for (int n = 0; n < 8; ++n) {
                    float2v zz; zz[0] = acc[n][0]; zz[1] = acc[n][1];
                    *(float2v*)&zring[sp][g][n * 16 + l15][0] = zz;
                }
            }
        }
        BAR();  // S1: gact (and zring slot t+4) published

        // ---------------- Phase B ----------------
        if (!prod) {
            // cell update: 1 (row,col) per lane across waves 0-3 — no scan
            const float f  = gact[crow][0][ccol];
            const float i_ = gact[crow][1][ccol];
            const float g_ = gact[crow][2][ccol];
            const float o_ = gact[crow][3][ccol];
            const float cn = fmaf(f, c_reg, i_ * g_);
            const float hn = o_ * fast_tanh(cn);
            c_reg = cn; h_last = hn;
            h_bf[crow][ccol] = f2bf(hn);
            out[((size_t)t * BATCH + b0 + crow) * HID + ccol] = hn;
        } else if (wid == 4) {
            // stage x[t+5] (prefetched), prefetch x[t+6]
            if (t + 5 < SEQ) {
                unsigned* dst = (unsigned*)&x_bf[lane >> 5][(lane & 31) * 4];
                dst[0] = (unsigned)f2bf(xv[0]) | ((unsigned)f2bf(xv[1]) << 16);
                dst[1] = (unsigned)f2bf(xv[2]) | ((unsigned)f2bf(xv[3]) << 16);
                if (t + 6 < SEQ)
                    xv = *(const float4v*)(X + ((size_t)(t + 6) * BATCH + b0) * HID + lane * 4);
            }
        }
        BAR();  // S2: h_bf (and x_bf) ready
    }

    // final hx/cx tails (waves 0-3 hold last-step values per lane)
    if (!prod) {
        const size_t base = (size_t)SEQ * BATCH * HID;
        const size_t ro = (size_t)(b0 + crow) * HID + ccol;
        out[base + ro] = h_last;
        out[base + (size_t)BATCH * HID + ro] = c_reg;
    }
}

// ---------------------------------------------------------------------------
extern "C" void kernel_launch(void* const* d_in, const int* in_sizes, int n_in,
                              void* d_out, int out_size, void* d_ws, size_t ws_size,
                              hipStream_t stream) {
    const float* X  = (const float*)d_in[0];
    const float* Wf = (const float*)d_in[1];
    const float* bf = (const float*)d_in[2];
    const float* Wi = (const float*)d_in[3];
    const float* bi = (const float*)d_in[4];
    const float* Wg = (const float*)d_in[5];
    const float* bg = (const float*)d_in[6];
    const float* Wo = (const float*)d_in[7];
    const float* bo = (const float*)d_in[8];
    float* out = (float*)d_out;
    (void)d_ws; (void)ws_size;

    qlstm_fused<<<BATCH / 2, 512, 0, stream>>>(
        X, Wf, bf, Wi, bi, Wg, bg, Wo, bo, out);
}